// Round 1
// baseline (505.915 us; speedup 1.0000x reference)
//
#include <hip/hip_runtime.h>
#include <cstdint>
#include <cstddef>

// ---------------------------------------------------------------------------
// GraphAttentionHead: out = elu(softmax(mask(LeakyReLU(mu_i + xi_j))) @ h)
//   h = features @ W_phi            [8192, 256]
//   mu = h @ w_mu = features @ (W_phi @ w_mu)   (p_mu trick)
//   scores are O(1) -> softmax needs no max subtraction; single pass computes
//   numerator (bf16 MFMA) and Z (fp32) together.  Adjacency (268 MB) is read
//   exactly once -> HBM roofline ~43 us for the attention kernel.
// ---------------------------------------------------------------------------

#define NN 8192
#define DIN 512
#define DOUT 256

typedef __attribute__((ext_vector_type(8))) short short8;   // 8 bf16 = 4 VGPRs
typedef __attribute__((ext_vector_type(4))) float floatx4;  // MFMA acc

using uint_as1 = __attribute__((address_space(1))) unsigned int;
using uint_as3 = __attribute__((address_space(3))) unsigned int;

__device__ __forceinline__ void gld_lds16(const void* g, void* l) {
  // async global->LDS, 16B/lane; LDS dest = wave-uniform base + lane*16
  __builtin_amdgcn_global_load_lds((const uint_as1*)g, (uint_as3*)l, 16, 0, 0);
}

__device__ __forceinline__ unsigned short f2b(float f) {  // fp32 -> bf16 RNE (finite inputs)
  unsigned u = __float_as_uint(f);
  u += 0x7fffu + ((u >> 16) & 1u);
  return (unsigned short)(u >> 16);
}
__device__ __forceinline__ float b2f(short s) {
  return __uint_as_float(((unsigned)(unsigned short)s) << 16);
}

// --------------------------- K0a: features -> bf16 -------------------------
__global__ void k_cvt_features(const float* __restrict__ f, unsigned short* __restrict__ fb) {
  int tid = blockIdx.x * 256 + threadIdx.x;           // 1,048,576 threads x 4 elems
  float4 v = ((const float4*)f)[tid];
  ushort4 o = {f2b(v.x), f2b(v.y), f2b(v.z), f2b(v.w)};
  *(ushort4*)&fb[tid * 4] = o;
}

// ------------------- K0b: W_phi [512][256] -> Wt bf16 [256][512] ------------
__global__ void k_prep_wt(const float* __restrict__ w, unsigned short* __restrict__ wt) {
  int tid = blockIdx.x * 256 + threadIdx.x;           // 131072
  int n = tid >> 9, k = tid & 511;
  wt[n * 512 + k] = f2b(w[k * 256 + n]);
}

// ----------------- K0c: p_mu = W_phi @ w_mu, p_xi = W_phi @ w_xi ------------
__global__ void k_prep_p(const float* __restrict__ w, const float* __restrict__ wmu,
                         const float* __restrict__ wxi, float* __restrict__ pmu,
                         float* __restrict__ pxi) {
  int tid = blockIdx.x * 256 + threadIdx.x;           // 2048: 4 threads per k
  int k = tid >> 2, seg = tid & 3;
  float sm = 0.f, sx = 0.f;
  int base = k * 256 + seg * 64;
#pragma unroll
  for (int c = 0; c < 64; c += 4) {
    float4 wv = *(const float4*)&w[base + c];
    float4 mv = *(const float4*)&wmu[seg * 64 + c];
    float4 xv = *(const float4*)&wxi[seg * 64 + c];
    sm += wv.x * mv.x + wv.y * mv.y + wv.z * mv.z + wv.w * mv.w;
    sx += wv.x * xv.x + wv.y * xv.y + wv.z * xv.z + wv.w * xv.w;
  }
  sm += __shfl_xor(sm, 1); sm += __shfl_xor(sm, 2);
  sx += __shfl_xor(sx, 1); sx += __shfl_xor(sx, 2);
  if (seg == 0) { pmu[k] = sm; pxi[k] = sx; }
}

// ----------------- K2: mu/xi = features_bf @ p_mu / p_xi (wave per row) -----
__global__ void k_mu_xi(const unsigned short* __restrict__ fb, const float* __restrict__ pmu,
                        const float* __restrict__ pxi, float* __restrict__ mu,
                        float* __restrict__ xi) {
  int w = threadIdx.x >> 6, l = threadIdx.x & 63;
  int i = blockIdx.x * 4 + w;
  short8 fv = *(const short8*)&fb[i * 512 + l * 8];
  float m = 0.f, x = 0.f;
#pragma unroll
  for (int c = 0; c < 8; ++c) {
    float fvf = b2f(fv[c]);
    m = fmaf(fvf, pmu[l * 8 + c], m);
    x = fmaf(fvf, pxi[l * 8 + c], x);
  }
#pragma unroll
  for (int off = 32; off > 0; off >>= 1) {
    m += __shfl_xor(m, off);
    x += __shfl_xor(x, off);
  }
  if (l == 0) { mu[i] = m; xi[i] = x; }
}

// ------------- K1: h_t[n][m] = (features @ W_phi)^T, bf16 MFMA --------------
// BM=64, BN=128, BK=64; 4 waves, wave = 64m x 32n; grid 128x2 = 256 blocks.
__global__ __launch_bounds__(256, 2) void k_gemm1(const unsigned short* __restrict__ fb,
                                                  const unsigned short* __restrict__ wt,
                                                  unsigned short* __restrict__ ht) {
  __shared__ __align__(16) unsigned short As[64 * 64];   // [m][k] xor-swizzled granules
  __shared__ __align__(16) unsigned short Bs[128 * 64];  // [n][k] xor-swizzled granules
  int t = threadIdx.x, w = t >> 6, l = t & 63;
  int bm = blockIdx.x >> 1, bn = blockIdx.x & 1;
  int m0 = bm * 64, n0 = bn * 128;
  int lr = l >> 3, lg = l & 7, g = lg ^ lr;   // staging: phys granule lg holds logical g
  int kg = l >> 4, ln = l & 15;
  floatx4 zero = {0.f, 0.f, 0.f, 0.f};
  floatx4 acc[4][2];
#pragma unroll
  for (int mf = 0; mf < 4; ++mf)
#pragma unroll
    for (int nf = 0; nf < 2; ++nf) acc[mf][nf] = zero;

  for (int it = 0; it < 8; ++it) {
    int k0 = it * 64;
#pragma unroll
    for (int q = 0; q < 2; ++q) {  // A: 64 rows x 128B
      int row = w * 16 + q * 8 + lr;
      const void* gp = fb + (size_t)(m0 + row) * 512 + k0 + g * 8;
      int lb = __builtin_amdgcn_readfirstlane((w * 16 + q * 8) * 64);
      gld_lds16(gp, &As[lb]);
    }
#pragma unroll
    for (int q = 0; q < 4; ++q) {  // B: 128 rows x 128B
      int row = w * 32 + q * 8 + lr;
      const void* gp = wt + (size_t)(n0 + row) * 512 + k0 + g * 8;
      int lb = __builtin_amdgcn_readfirstlane((w * 32 + q * 8) * 64);
      gld_lds16(gp, &Bs[lb]);
    }
    __syncthreads();
#pragma unroll
    for (int ks = 0; ks < 2; ++ks) {
      int gg = ks * 4 + kg;
      int swz = (gg ^ (ln & 7)) * 8;
      short8 bfr[2];
#pragma unroll
      for (int nf = 0; nf < 2; ++nf)
        bfr[nf] = *(const short8*)&Bs[(w * 32 + nf * 16 + ln) * 64 + swz];
#pragma unroll
      for (int mf = 0; mf < 4; ++mf) {
        short8 afr = *(const short8*)&As[(mf * 16 + ln) * 64 + swz];
#pragma unroll
        for (int nf = 0; nf < 2; ++nf)
          acc[mf][nf] = __builtin_amdgcn_mfma_f32_16x16x32_bf16(afr, bfr[nf], acc[mf][nf], 0, 0, 0);
      }
    }
    __syncthreads();
  }
  // transposed store: h_t[n][m..m+3] <- acc rows (contiguous along m)
#pragma unroll
  for (int mf = 0; mf < 4; ++mf)
#pragma unroll
    for (int nf = 0; nf < 2; ++nf) {
      int ng = n0 + w * 32 + nf * 16 + ln;
      int mg = m0 + mf * 16 + kg * 4;
      ushort4 o = {f2b(acc[mf][nf][0]), f2b(acc[mf][nf][1]),
                   f2b(acc[mf][nf][2]), f2b(acc[mf][nf][3])};
      *(ushort4*)&ht[(size_t)ng * 8192 + mg] = o;
    }
}

// --------------------- K3: fused masked-softmax attention -------------------
// grid 512 blocks (2/CU), 256 thr (4 waves). i-tile 16, out tile 16x256,
// K-loop over all j in steps of 64. W-tile built on the fly; Z in registers.
__global__ __launch_bounds__(256, 2) void k_attn(const int* __restrict__ adj,
                                                 const unsigned short* __restrict__ ht,
                                                 const float* __restrict__ mu,
                                                 const float* __restrict__ xi,
                                                 float* __restrict__ out) {
  __shared__ __align__(16) unsigned short Bt[256 * 64];  // h_t tile [n][j], swizzled
  __shared__ __align__(16) unsigned short Wl[16 * 72];   // w tile [i][j], +8 pad
  __shared__ __align__(16) float xis[8192];              // all xi; reused as zbuf
  __shared__ float zinv[16];

  int t = threadIdx.x, w = t >> 6, l = t & 63;
  int i0 = blockIdx.x * 16;
  int rowi = t >> 4, col4 = (t & 15) * 4;
  int lr = l >> 3, lg = l & 7, g = lg ^ lr;
  int kg = l >> 4, ln = l & 15;

  float mu_t = mu[i0 + rowi];
#pragma unroll
  for (int c = 0; c < 8; ++c) {  // stage all 8192 xi into LDS
    int idx = c * 1024 + t * 4;
    *(float4*)&xis[idx] = *(const float4*)&xi[idx];
  }
  floatx4 zero = {0.f, 0.f, 0.f, 0.f};
  floatx4 acc[4];
#pragma unroll
  for (int nf = 0; nf < 4; ++nf) acc[nf] = zero;
  float zsum = 0.f;
  const int* adjrow = adj + (size_t)(i0 + rowi) * 8192 + col4;
  __syncthreads();

  for (int it = 0; it < 128; ++it) {
    int j0 = it * 64;
    // --- build W tile: w = adj ? exp(LeakyReLU(mu_i + xi_j)) : 0 ---
    int4 a4 = *(const int4*)(adjrow + j0);
    float4 xv = *(const float4*)&xis[j0 + col4];
    float s0 = mu_t + xv.x, s1 = mu_t + xv.y, s2 = mu_t + xv.z, s3 = mu_t + xv.w;
    s0 = fmaxf(s0, 0.2f * s0); s1 = fmaxf(s1, 0.2f * s1);
    s2 = fmaxf(s2, 0.2f * s2); s3 = fmaxf(s3, 0.2f * s3);
    float e0 = __builtin_amdgcn_exp2f(s0 * 1.44269504f);
    float e1 = __builtin_amdgcn_exp2f(s1 * 1.44269504f);
    float e2 = __builtin_amdgcn_exp2f(s2 * 1.44269504f);
    float e3 = __builtin_amdgcn_exp2f(s3 * 1.44269504f);
    float w0 = (a4.x != 0) ? e0 : 0.f;
    float w1 = (a4.y != 0) ? e1 : 0.f;
    float w2 = (a4.z != 0) ? e2 : 0.f;
    float w3 = (a4.w != 0) ? e3 : 0.f;
    zsum += (w0 + w1) + (w2 + w3);
    ushort4 wp = {f2b(w0), f2b(w1), f2b(w2), f2b(w3)};
    *(ushort4*)&Wl[rowi * 72 + col4] = wp;
    // --- stage h_t tile [256 n][64 j] via async global->LDS ---
#pragma unroll
    for (int q = 0; q < 8; ++q) {
      int n = w * 64 + q * 8 + lr;
      const void* gp = ht + (size_t)n * 8192 + j0 + g * 8;
      int lb = __builtin_amdgcn_readfirstlane((w * 64 + q * 8) * 64);
      gld_lds16(gp, &Bt[lb]);
    }
    __syncthreads();
    // --- MFMA: wave w covers out cols [w*64, w*64+64) ---
#pragma unroll
    for (int ks = 0; ks < 2; ++ks) {
      int gg = ks * 4 + kg;
      short8 afr = *(const short8*)&Wl[ln * 72 + gg * 8];
#pragma unroll
      for (int nf = 0; nf < 4; ++nf) {
        int n = w * 64 + nf * 16 + ln;
        short8 bfr = *(const short8*)&Bt[n * 64 + ((gg ^ (ln & 7)) * 8)];
        acc[nf] = __builtin_amdgcn_mfma_f32_16x16x32_bf16(afr, bfr, acc[nf], 0, 0, 0);
      }
    }
    __syncthreads();
  }

  // --- Z reduction: 16 partials per row ---
  float* zb = xis;  // xi no longer needed
  zb[t] = zsum;
  __syncthreads();
  if (t < 16) {
    float s = 0.f;
#pragma unroll
    for (int q = 0; q < 16; ++q) s += zb[t * 16 + q];
    zinv[t] = 1.0f / s;
  }
  __syncthreads();

  // --- epilogue: out = elu(acc / Z) ---
#pragma unroll
  for (int nf = 0; nf < 4; ++nf) {
    int col = w * 64 + nf * 16 + ln;
#pragma unroll
    for (int r = 0; r < 4; ++r) {
      int row = kg * 4 + r;
      float v = acc[nf][r] * zinv[row];
      v = (v > 0.f) ? v : (__builtin_amdgcn_exp2f(v * 1.44269504f) - 1.f);
      out[(size_t)(i0 + row) * 256 + col] = v;
    }
  }
}

// ---------------------------------------------------------------------------
extern "C" void kernel_launch(void* const* d_in, const int* in_sizes, int n_in,
                              void* d_out, int out_size, void* d_ws, size_t ws_size,
                              hipStream_t stream) {
  const float* features = (const float*)d_in[0];
  const int* adjm = (const int*)d_in[1];
  const float* W_phi = (const float*)d_in[2];
  const float* w_mu = (const float*)d_in[3];
  const float* w_xi = (const float*)d_in[4];
  float* out = (float*)d_out;

  char* ws = (char*)d_ws;
  unsigned short* fb  = (unsigned short*)(ws + 0);         // 8192x512 bf16 = 8 MB
  unsigned short* ht  = (unsigned short*)(ws + 8388608);   // 256x8192 bf16 = 4 MB
  unsigned short* wt  = (unsigned short*)(ws + 12582912);  // 256x512 bf16 = 256 KB
  float* pmu = (float*)(ws + 12845056);                    // 512 f32
  float* pxi = (float*)(ws + 12847104);                    // 512 f32
  float* muv = (float*)(ws + 12849152);                    // 8192 f32
  float* xiv = (float*)(ws + 12881920);                    // 8192 f32

  k_cvt_features<<<4096, 256, 0, stream>>>(features, fb);
  k_prep_wt<<<512, 256, 0, stream>>>(W_phi, wt);
  k_prep_p<<<8, 256, 0, stream>>>(W_phi, w_mu, w_xi, pmu, pxi);
  k_mu_xi<<<2048, 256, 0, stream>>>(fb, pmu, pxi, muv, xiv);
  k_gemm1<<<256, 256, 0, stream>>>(fb, wt, ht);
  k_attn<<<512, 256, 0, stream>>>(adjm, ht, muv, xiv, out);
}